// Round 1
// baseline (2666.829 us; speedup 1.0000x reference)
//
#include <hip/hip_runtime.h>

// ---------------------------------------------------------------------------
// InteractionBlock: W = ssp(attr@w1+b1)@w2+b2; W *= cutoff(len);
// h = x@lin1_w; agg[dst] += h[src]*W; out = ssp(agg@lin2_w+b)@lin_w+b
// N=50000, E=1.6M, HID=NF=128, NG=64
// ---------------------------------------------------------------------------

static __device__ __forceinline__ float sspf(float v) {
    // logaddexp(v,0) - log(2), numerically stable
    return fmaxf(v, 0.0f) + __logf(1.0f + __expf(-fabsf(v))) - 0.69314718f;
}

// round-to-nearest-even fp32 -> bf16 (returns low 16 bits)
static __device__ __forceinline__ unsigned bf16rn(float x) {
    unsigned u = __builtin_bit_cast(unsigned, x);
    return (u + 0x7fffu + ((u >> 16) & 1u)) >> 16;
}
static __device__ __forceinline__ float bflo(unsigned p) {
    return __builtin_bit_cast(float, p << 16);
}
static __device__ __forceinline__ float bfhi(unsigned p) {
    return __builtin_bit_cast(float, p & 0xffff0000u);
}
static __device__ __forceinline__ float rdlane(float v, int l) {
    return __builtin_bit_cast(float, __builtin_amdgcn_readlane(__builtin_bit_cast(int, v), l));
}

// ---------------------------------------------------------------------------
// Kernel 1: h = x @ lin1_w   [N,128] = [N,128]@[128,128]
// 16 rows per 256-thread block; thread owns (col j, 8 rows)
// ---------------------------------------------------------------------------
__global__ __launch_bounds__(256) void node_proj_kernel(
    const float* __restrict__ x, const float* __restrict__ w,
    float* __restrict__ h, int n)
{
    __shared__ float xs[16 * 128];
    int row0 = blockIdx.x * 16;
    for (int i = threadIdx.x; i < 16 * 128; i += 256) {
        int r = row0 + (i >> 7);
        xs[i] = (r < n) ? x[(size_t)r * 128 + (i & 127)] : 0.0f;
    }
    __syncthreads();
    int j = threadIdx.x & 127;
    int rb = (threadIdx.x >> 7) * 8;
    float acc[8] = {0, 0, 0, 0, 0, 0, 0, 0};
    for (int k = 0; k < 128; ++k) {
        float wk = w[k * 128 + j];
#pragma unroll
        for (int r = 0; r < 8; ++r)
            acc[r] = fmaf(xs[(rb + r) * 128 + k], wk, acc[r]);
    }
#pragma unroll
    for (int r = 0; r < 8; ++r) {
        int rr = row0 + rb + r;
        if (rr < n) h[(size_t)rr * 128 + j] = acc[r];
    }
}

// ---------------------------------------------------------------------------
// Kernel 2: fused per-edge filter-MLP + cutoff + gather(h[src]) + scatter(agg[dst])
// One wave (64 lanes) per edge; lane owns output cols (lane, lane+64).
// w1,w2 staged in LDS as bf16 pairs (j, j+64) packed in u32: 48 KB total.
// ---------------------------------------------------------------------------
__global__ __launch_bounds__(1024, 8) void edge_kernel(
    const float* __restrict__ eattr, const int* __restrict__ eidx,
    const float* __restrict__ elen,
    const float* __restrict__ w1, const float* __restrict__ b1,
    const float* __restrict__ w2, const float* __restrict__ b2,
    const float* __restrict__ h, float* __restrict__ agg, int E)
{
    __shared__ unsigned lw1[64 * 64];   // 16 KB: pack(w1[k][c], w1[k][c+64])
    __shared__ unsigned lw2[128 * 64];  // 32 KB: pack(w2[i][c], w2[i][c+64])
    for (int i = threadIdx.x; i < 64 * 64; i += 1024) {
        int k = i >> 6, c = i & 63;
        lw1[i] = bf16rn(w1[k * 128 + c]) | (bf16rn(w1[k * 128 + c + 64]) << 16);
    }
    for (int i = threadIdx.x; i < 128 * 64; i += 1024) {
        int k = i >> 6, c = i & 63;
        lw2[i] = bf16rn(w2[k * 128 + c]) | (bf16rn(w2[k * 128 + c + 64]) << 16);
    }
    __syncthreads();

    int lane = threadIdx.x & 63;
    int wid = blockIdx.x * 16 + (threadIdx.x >> 6);
    int stride = gridDim.x * 16;
    float bb1a = b1[lane], bb1b = b1[lane + 64];
    float bb2a = b2[lane], bb2b = b2[lane + 64];

    for (int e = wid; e < E; e += stride) {
        float len = elen[e];
        if (len > 10.0f || len < 0.0f) continue;  // cutoff: whole edge contributes 0
        float cv = 0.5f * (__cosf(len * 0.31415927f) + 1.0f);

        // layer 1: u = attr @ w1 + b1  (lane i holds attr[i], broadcast via readlane)
        float av = eattr[(size_t)e * 64 + lane];
        float u1 = bb1a, u2 = bb1b;
#pragma unroll
        for (int k = 0; k < 64; ++k) {
            float ak = rdlane(av, k);
            unsigned p = lw1[k * 64 + lane];
            u1 = fmaf(ak, bflo(p), u1);
            u2 = fmaf(ak, bfhi(p), u2);
        }
        float t1 = sspf(u1), t2 = sspf(u2);

        // layer 2: W = t @ w2 + b2
        float wa = bb2a, wb = bb2b;
#pragma unroll
        for (int i = 0; i < 64; ++i) {
            float ti = rdlane(t1, i);   // t[i]
            float tj = rdlane(t2, i);   // t[i+64]
            unsigned pa = lw2[i * 64 + lane];
            unsigned pb = lw2[(i + 64) * 64 + lane];
            wa = fmaf(ti, bflo(pa), wa);
            wa = fmaf(tj, bflo(pb), wa);
            wb = fmaf(ti, bfhi(pa), wb);
            wb = fmaf(tj, bfhi(pb), wb);
        }
        wa *= cv;
        wb *= cv;

        int s = eidx[e];
        int d = eidx[E + e];
        float h1 = h[(size_t)s * 128 + lane];
        float h2 = h[(size_t)s * 128 + lane + 64];
        atomicAdd(&agg[(size_t)d * 128 + lane], h1 * wa);
        atomicAdd(&agg[(size_t)d * 128 + lane + 64], h2 * wb);
    }
}

// ---------------------------------------------------------------------------
// Kernel 3: out = ssp(agg @ lin2_w + lin2_b) @ lin_w + lin_b
// ---------------------------------------------------------------------------
__global__ __launch_bounds__(256) void out_kernel(
    const float* __restrict__ agg,
    const float* __restrict__ w2, const float* __restrict__ b2,
    const float* __restrict__ w3, const float* __restrict__ b3,
    float* __restrict__ out, int n)
{
    __shared__ float sin_[16 * 128];
    __shared__ float smid[16 * 128];
    int row0 = blockIdx.x * 16;
    for (int i = threadIdx.x; i < 16 * 128; i += 256) {
        int r = row0 + (i >> 7);
        sin_[i] = (r < n) ? agg[(size_t)r * 128 + (i & 127)] : 0.0f;
    }
    __syncthreads();
    int j = threadIdx.x & 127;
    int rb = (threadIdx.x >> 7) * 8;
    float acc[8];
    float bj = b2[j];
#pragma unroll
    for (int r = 0; r < 8; ++r) acc[r] = bj;
    for (int k = 0; k < 128; ++k) {
        float wk = w2[k * 128 + j];
#pragma unroll
        for (int r = 0; r < 8; ++r)
            acc[r] = fmaf(sin_[(rb + r) * 128 + k], wk, acc[r]);
    }
#pragma unroll
    for (int r = 0; r < 8; ++r) smid[(rb + r) * 128 + j] = sspf(acc[r]);
    __syncthreads();
    float bj3 = b3[j];
#pragma unroll
    for (int r = 0; r < 8; ++r) acc[r] = bj3;
    for (int k = 0; k < 128; ++k) {
        float wk = w3[k * 128 + j];
#pragma unroll
        for (int r = 0; r < 8; ++r)
            acc[r] = fmaf(smid[(rb + r) * 128 + k], wk, acc[r]);
    }
#pragma unroll
    for (int r = 0; r < 8; ++r) {
        int rr = row0 + rb + r;
        if (rr < n) out[(size_t)rr * 128 + j] = acc[r];
    }
}

// ---------------------------------------------------------------------------
extern "C" void kernel_launch(void* const* d_in, const int* in_sizes, int n_in,
                              void* d_out, int out_size, void* d_ws, size_t ws_size,
                              hipStream_t stream)
{
    const float* x     = (const float*)d_in[0];
    const int*   eidx  = (const int*)d_in[1];
    const float* elen  = (const float*)d_in[2];
    const float* eattr = (const float*)d_in[3];
    const float* lin1w = (const float*)d_in[4];
    const float* nnw1  = (const float*)d_in[5];
    const float* nnb1  = (const float*)d_in[6];
    const float* nnw2  = (const float*)d_in[7];
    const float* nnb2  = (const float*)d_in[8];
    const float* lin2w = (const float*)d_in[9];
    const float* lin2b = (const float*)d_in[10];
    const float* linw  = (const float*)d_in[11];
    const float* linb  = (const float*)d_in[12];

    int n = in_sizes[0] / 128;   // 50000
    int E = in_sizes[2];         // 1.6M

    float* h   = (float*)d_ws;           // n*128 floats
    float* agg = h + (size_t)n * 128;    // n*128 floats

    hipMemsetAsync(agg, 0, (size_t)n * 128 * sizeof(float), stream);

    node_proj_kernel<<<(n + 15) / 16, 256, 0, stream>>>(x, lin1w, h, n);
    edge_kernel<<<512, 1024, 0, stream>>>(eattr, eidx, elen,
                                          nnw1, nnb1, nnw2, nnb2, h, agg, E);
    out_kernel<<<(n + 15) / 16, 256, 0, stream>>>(agg, lin2w, lin2b, linw, linb,
                                                  (float*)d_out, n);
}

// Round 2
// 1247.515 us; speedup vs baseline: 2.1377x; 2.1377x over previous
//
#include <hip/hip_runtime.h>

// ---------------------------------------------------------------------------
// InteractionBlock: W = ssp(attr@w1+b1)@w2+b2; W *= cutoff(len);
// h = x@lin1_w; agg[dst] += h[src]*W; out = ssp(agg@lin2_w+b)@lin_w+b
// N=50000, E=1.6M, HID=NF=128, NG=64
// R2: edge MLP on MFMA (16 edges/wave, 16x16x32 bf16), m120-style LDS
//     round-trip between layers; node GEMMs use transposed-LDS broadcast reads.
// ---------------------------------------------------------------------------

typedef __attribute__((ext_vector_type(8))) short bf16x8;
typedef __attribute__((ext_vector_type(4))) float f32x4;

static __device__ __forceinline__ float sspf(float v) {
    return fmaxf(v, 0.0f) + __logf(1.0f + __expf(-fabsf(v))) - 0.69314718f;
}

// fp32 -> bf16 round-to-nearest-even
static __device__ __forceinline__ short bf16s(float x) {
    unsigned u = __builtin_bit_cast(unsigned, x);
    return (short)((u + 0x7fffu + ((u >> 16) & 1u)) >> 16);
}

// ---------------------------------------------------------------------------
// Kernel 1: h = x @ lin1_w   [N,128] = [N,128]@[128,128]  (fp32 vector)
// x-tile stored transposed in LDS (pitch 20) -> per-k reads are wave-broadcast
// ds_read_b128 (8 rows as 2 x float4).
// ---------------------------------------------------------------------------
__global__ __launch_bounds__(256) void node_proj_kernel(
    const float* __restrict__ x, const float* __restrict__ w,
    float* __restrict__ h, int n)
{
    __shared__ float xsT[128 * 20];   // [k][row], pitch 20 floats (80 B, 16B-aligned)
    int row0 = blockIdx.x * 16;
    for (int i = threadIdx.x; i < 2048; i += 256) {
        int r = i >> 7, c = i & 127;
        int rr = row0 + r;
        xsT[c * 20 + r] = (rr < n) ? x[(size_t)rr * 128 + c] : 0.0f;
    }
    __syncthreads();
    int j = threadIdx.x & 127;
    int rb = (threadIdx.x >> 7) * 8;
    float acc[8] = {0, 0, 0, 0, 0, 0, 0, 0};
    for (int k = 0; k < 128; ++k) {
        float wk = w[k * 128 + j];
        const float4* xp = (const float4*)&xsT[k * 20 + rb];
        float4 u0 = xp[0], u1 = xp[1];
        acc[0] = fmaf(u0.x, wk, acc[0]);
        acc[1] = fmaf(u0.y, wk, acc[1]);
        acc[2] = fmaf(u0.z, wk, acc[2]);
        acc[3] = fmaf(u0.w, wk, acc[3]);
        acc[4] = fmaf(u1.x, wk, acc[4]);
        acc[5] = fmaf(u1.y, wk, acc[5]);
        acc[6] = fmaf(u1.z, wk, acc[6]);
        acc[7] = fmaf(u1.w, wk, acc[7]);
    }
#pragma unroll
    for (int r = 0; r < 8; ++r) {
        int rr = row0 + rb + r;
        if (rr < n) h[(size_t)rr * 128 + j] = acc[r];
    }
}

// ---------------------------------------------------------------------------
// Kernel 2: fused edge MLP (MFMA) + cutoff + gather/scatter.
// 512 threads = 8 waves/block; each wave does 16 edges per group iteration.
// mfma_f32_16x16x32_bf16:  A[m=lane&15][k=(lane>>4)*8+j],
//                          B[k=(lane>>4)*8+j][n=lane&15],
//                          C/D: row(M)=(lane>>4)*4+reg, col(N)=lane&15.
// ---------------------------------------------------------------------------
__global__ __launch_bounds__(512, 4) void edge_kernel(
    const float* __restrict__ eattr, const int* __restrict__ eidx,
    const float* __restrict__ elen,
    const float* __restrict__ w1, const float* __restrict__ b1,
    const float* __restrict__ w2, const float* __restrict__ b2,
    const float* __restrict__ h, float* __restrict__ agg, int E)
{
    // Transposed weights in LDS, bf16. Pitches give 16B-aligned b128 frags
    // and <=2-way bank aliasing (free).
    __shared__ short w1T[128 * 72];       // w1T[n][k], k<64   : 18 KB
    __shared__ short w2T[128 * 136];      // w2T[n][k], k<128  : 34 KB
    __shared__ short tseg[8 * 16 * 40];   // per-wave [edge][c], c<32 : 10 KB

    for (int i = threadIdx.x; i < 64 * 128; i += 512) {
        int k = i >> 7, nn = i & 127;
        w1T[nn * 72 + k] = bf16s(w1[i]);
    }
    for (int i = threadIdx.x; i < 128 * 128; i += 512) {
        int k = i >> 7, nn = i & 127;
        w2T[nn * 136 + k] = bf16s(w2[i]);
    }
    __syncthreads();

    const int lane = threadIdx.x & 63;
    const int m = lane & 15;        // edge (A rows / C col-group partner)
    const int q = lane >> 4;        // k-quad
    short* tw = tseg + (threadIdx.x >> 6) * (16 * 40);

    // per-lane bias values for its output columns: col = 16*u + m
    float b1v[8], b2v[8];
#pragma unroll
    for (int u = 0; u < 8; ++u) {
        b1v[u] = b1[u * 16 + m];
        b2v[u] = b2[u * 16 + m];
    }

    const int ngroups = (E + 15) >> 4;
    int wid = blockIdx.x * 8 + (threadIdx.x >> 6);
    int stride = gridDim.x * 8;

    for (int g = wid; g < ngroups; g += stride) {
        int e0 = g << 4;

        // ---- A fragments from eattr (row = edge e0+m, k = a*32 + q*8 + j)
        int erow = e0 + m;
        if (erow >= E) erow = E - 1;
        const float* ap = eattr + (size_t)erow * 64 + q * 8;
        float4 x0 = *(const float4*)(ap);
        float4 x1 = *(const float4*)(ap + 4);
        float4 x2 = *(const float4*)(ap + 32);
        float4 x3 = *(const float4*)(ap + 36);
        bf16x8 af0, af1;
        af0[0] = bf16s(x0.x); af0[1] = bf16s(x0.y);
        af0[2] = bf16s(x0.z); af0[3] = bf16s(x0.w);
        af0[4] = bf16s(x1.x); af0[5] = bf16s(x1.y);
        af0[6] = bf16s(x1.z); af0[7] = bf16s(x1.w);
        af1[0] = bf16s(x2.x); af1[1] = bf16s(x2.y);
        af1[2] = bf16s(x2.z); af1[3] = bf16s(x2.w);
        af1[4] = bf16s(x3.x); af1[5] = bf16s(x3.y);
        af1[6] = bf16s(x3.z); af1[7] = bf16s(x3.w);

        // ---- per-edge meta for this lane's 4 epilogue edges (e0 + 4q + r)
        float cvv[4];
        int sV[4], dV[4];
#pragma unroll
        for (int r = 0; r < 4; ++r) {
            int e = e0 + 4 * q + r;
            int ec = (e < E) ? e : 0;
            float len = elen[ec];
            sV[r] = eidx[ec];
            dV[r] = eidx[E + ec];
            bool ok = (e < E) && (len <= 10.0f) && (len >= 0.0f);
            cvv[r] = ok ? 0.5f * (__cosf(len * 0.31415927f) + 1.0f) : 0.0f;
        }

        // ---- layer-2 accumulators (W), init with b2
        f32x4 acc2[8];
#pragma unroll
        for (int nt = 0; nt < 8; ++nt) {
            f32x4 c; c[0] = b2v[nt]; c[1] = b2v[nt]; c[2] = b2v[nt]; c[3] = b2v[nt];
            acc2[nt] = c;
        }

        // ---- fused layer1 -> ssp -> layer2, 32 t-columns at a time
#pragma unroll
        for (int k2 = 0; k2 < 4; ++k2) {
            f32x4 acc1[2];
#pragma unroll
            for (int t = 0; t < 2; ++t) {
                float bv = b1v[2 * k2 + t];
                f32x4 c; c[0] = bv; c[1] = bv; c[2] = bv; c[3] = bv;
                acc1[t] = c;
            }
#pragma unroll
            for (int t = 0; t < 2; ++t) {
#pragma unroll
                for (int a = 0; a < 2; ++a) {
                    bf16x8 bw = *(const bf16x8*)&w1T[(16 * (2 * k2 + t) + m) * 72 + a * 32 + q * 8];
                    acc1[t] = __builtin_amdgcn_mfma_f32_16x16x32_bf16(
                        (a == 0) ? af0 : af1, bw, acc1[t], 0, 0, 0);
                }
            }
            // ssp + pack to bf16, write to per-wave tseg [edge][c], c = 16t+m
#pragma unroll
            for (int t = 0; t < 2; ++t) {
#pragma unroll
                for (int r = 0; r < 4; ++r) {
                    tw[(4 * q + r) * 40 + 16 * t + m] = bf16s(sspf(acc1[t][r]));
                }
            }
            // A-fragment of t for layer 2 (compiler inserts lgkmcnt wait)
            bf16x8 ta = *(const bf16x8*)&tw[m * 40 + q * 8];
#pragma unroll
            for (int nt = 0; nt < 8; ++nt) {
                bf16x8 bw2 = *(const bf16x8*)&w2T[(16 * nt + m) * 136 + k2 * 32 + q * 8];
                acc2[nt] = __builtin_amdgcn_mfma_f32_16x16x32_bf16(ta, bw2, acc2[nt], 0, 0, 0);
            }
        }

        // ---- epilogue: W *= cv; agg[dst][col] += h[src][col] * W
        // lane holds cols 16*nt + m for edges e0 + 4q + r (reg r)
#pragma unroll
        for (int r = 0; r < 4; ++r) {
            float cv = cvv[r];
            if (cv != 0.0f) {
                const float* hp = h + (size_t)sV[r] * 128 + m;
                float* gp = agg + (size_t)dV[r] * 128 + m;
#pragma unroll
                for (int nt = 0; nt < 8; ++nt) {
                    float Wv = acc2[nt][r] * cv;
                    atomicAdd(gp + nt * 16, hp[nt * 16] * Wv);
                }
            }
        }
    }
}

// ---------------------------------------------------------------------------
// Kernel 3: out = ssp(agg @ lin2_w + lin2_b) @ lin_w + lin_b  (fp32 vector)
// ---------------------------------------------------------------------------
__global__ __launch_bounds__(256) void out_kernel(
    const float* __restrict__ agg,
    const float* __restrict__ w2, const float* __restrict__ b2,
    const float* __restrict__ w3, const float* __restrict__ b3,
    float* __restrict__ out, int n)
{
    __shared__ float aT[128 * 20];   // agg tile transposed [k][row]
    __shared__ float mT[128 * 20];   // mid tile transposed [k][row]
    int row0 = blockIdx.x * 16;
    for (int i = threadIdx.x; i < 2048; i += 256) {
        int r = i >> 7, c = i & 127;
        int rr = row0 + r;
        aT[c * 20 + r] = (rr < n) ? agg[(size_t)rr * 128 + c] : 0.0f;
    }
    __syncthreads();
    int j = threadIdx.x & 127;
    int rb = (threadIdx.x >> 7) * 8;

    float acc[8];
    float bj = b2[j];
#pragma unroll
    for (int r = 0; r < 8; ++r) acc[r] = bj;
    for (int k = 0; k < 128; ++k) {
        float wk = w2[k * 128 + j];
        const float4* xp = (const float4*)&aT[k * 20 + rb];
        float4 u0 = xp[0], u1 = xp[1];
        acc[0] = fmaf(u0.x, wk, acc[0]);
        acc[1] = fmaf(u0.y, wk, acc[1]);
        acc[2] = fmaf(u0.z, wk, acc[2]);
        acc[3] = fmaf(u0.w, wk, acc[3]);
        acc[4] = fmaf(u1.x, wk, acc[4]);
        acc[5] = fmaf(u1.y, wk, acc[5]);
        acc[6] = fmaf(u1.z, wk, acc[6]);
        acc[7] = fmaf(u1.w, wk, acc[7]);
    }
    // mid = ssp(acc), store transposed: mT[j][rb..rb+7]
    float4 s0, s1;
    s0.x = sspf(acc[0]); s0.y = sspf(acc[1]); s0.z = sspf(acc[2]); s0.w = sspf(acc[3]);
    s1.x = sspf(acc[4]); s1.y = sspf(acc[5]); s1.z = sspf(acc[6]); s1.w = sspf(acc[7]);
    ((float4*)&mT[j * 20 + rb])[0] = s0;
    ((float4*)&mT[j * 20 + rb])[1] = s1;
    __syncthreads();

    float bj3 = b3[j];
#pragma unroll
    for (int r = 0; r < 8; ++r) acc[r] = bj3;
    for (int k = 0; k < 128; ++k) {
        float wk = w3[k * 128 + j];
        const float4* xp = (const float4*)&mT[k * 20 + rb];
        float4 u0 = xp[0], u1 = xp[1];
        acc[0] = fmaf(u0.x, wk, acc[0]);
        acc[1] = fmaf(u0.y, wk, acc[1]);
        acc[2] = fmaf(u0.z, wk, acc[2]);
        acc[3] = fmaf(u0.w, wk, acc[3]);
        acc[4] = fmaf(u1.x, wk, acc[4]);
        acc[5] = fmaf(u1.y, wk, acc[5]);
        acc[6] = fmaf(u1.z, wk, acc[6]);
        acc[7] = fmaf(u1.w, wk, acc[7]);
    }
#pragma unroll
    for (int r = 0; r < 8; ++r) {
        int rr = row0 + rb + r;
        if (rr < n) out[(size_t)rr * 128 + j] = acc[r];
    }
}

// ---------------------------------------------------------------------------
extern "C" void kernel_launch(void* const* d_in, const int* in_sizes, int n_in,
                              void* d_out, int out_size, void* d_ws, size_t ws_size,
                              hipStream_t stream)
{
    const float* x     = (const float*)d_in[0];
    const int*   eidx  = (const int*)d_in[1];
    const float* elen  = (const float*)d_in[2];
    const float* eattr = (const float*)d_in[3];
    const float* lin1w = (const float*)d_in[4];
    const float* nnw1  = (const float*)d_in[5];
    const float* nnb1  = (const float*)d_in[6];
    const float* nnw2  = (const float*)d_in[7];
    const float* nnb2  = (const float*)d_in[8];
    const float* lin2w = (const float*)d_in[9];
    const float* lin2b = (const float*)d_in[10];
    const float* linw  = (const float*)d_in[11];
    const float* linb  = (const float*)d_in[12];

    int n = in_sizes[0] / 128;   // 50000
    int E = in_sizes[2];         // 1.6M

    float* h   = (float*)d_ws;           // n*128 floats
    float* agg = h + (size_t)n * 128;    // n*128 floats

    hipMemsetAsync(agg, 0, (size_t)n * 128 * sizeof(float), stream);

    node_proj_kernel<<<(n + 15) / 16, 256, 0, stream>>>(x, lin1w, h, n);
    edge_kernel<<<512, 512, 0, stream>>>(eattr, eidx, elen,
                                         nnw1, nnb1, nnw2, nnb2, h, agg, E);
    out_kernel<<<(n + 15) / 16, 256, 0, stream>>>(agg, lin2w, lin2b, linw, linb,
                                                  (float*)d_out, n);
}